// Round 1
// baseline (1273.890 us; speedup 1.0000x reference)
//
#include <hip/hip_runtime.h>
#include <hip/hip_bf16.h>

// ---------------------------------------------------------------------------
// GCN encoder (4 conv layers, shared CSR graph) + 3-layer MLP decoder.
// Round 1: correctness-first fp32. CSR built per call (ws re-poisoned).
// ---------------------------------------------------------------------------

#define WAVE 64

// ---- graph build ----------------------------------------------------------

__global__ void count_kernel(const int* __restrict__ dst, int* __restrict__ counts, int E) {
    int e = blockIdx.x * 256 + threadIdx.x;
    if (e < E) atomicAdd(&counts[dst[e]], 1);
}

// single-block scan: exclusive prefix over counts -> rowptr, fillcur
__global__ void scan_kernel(const int* __restrict__ counts, int* __restrict__ rowptr,
                            int* __restrict__ fillcur, int n, int e_total) {
    __shared__ int wsum[16];
    __shared__ int carry_s;
    int tid  = threadIdx.x;
    int lane = tid & 63, wid = tid >> 6;
    if (tid == 0) carry_s = 0;
    __syncthreads();
    for (int base = 0; base < n; base += 1024) {
        int i = base + tid;
        int v = (i < n) ? counts[i] : 0;
        int s = v;
        #pragma unroll
        for (int off = 1; off < 64; off <<= 1) {
            int u = __shfl_up(s, off);
            if (lane >= off) s += u;
        }
        if (lane == 63) wsum[wid] = s;
        __syncthreads();
        int wave_off = 0;
        #pragma unroll
        for (int w = 0; w < 16; ++w)
            if (w < wid) wave_off += wsum[w];
        int carry = carry_s;
        int excl  = carry + wave_off + s - v;
        if (i < n) { rowptr[i] = excl; fillcur[i] = excl; }
        __syncthreads();
        if (tid == 1023) carry_s = carry + wave_off + s;
        __syncthreads();
    }
    if (tid == 0) rowptr[n] = e_total;
}

__global__ void fill_kernel(const int* __restrict__ src, const int* __restrict__ dst,
                            int* __restrict__ fillcur, int* __restrict__ col, int E) {
    int e = blockIdx.x * 256 + threadIdx.x;
    if (e < E) {
        int pos = atomicAdd(&fillcur[dst[e]], 1);
        col[pos] = src[e];
    }
}

__global__ void dinv_kernel(const int* __restrict__ counts, float* __restrict__ dinv, int n) {
    int i = blockIdx.x * 256 + threadIdx.x;
    if (i < n) dinv[i] = rsqrtf((float)(counts[i] + 1));   // +1 self loop
}

// ---- input layer: t = x @ W_s  (N x 3 @ 3 x 128) --------------------------

__global__ void in_gemm_kernel(const float* __restrict__ x, const float* __restrict__ W,
                               float* __restrict__ t, int n) {
    int g = blockIdx.x * 256 + threadIdx.x;
    int i = g >> 7, c = g & 127;
    if (i < n) {
        float x0 = x[i*3+0], x1 = x[i*3+1], x2 = x[i*3+2];
        t[(size_t)i*128 + c] = x0*W[c] + x1*W[128+c] + x2*W[256+c];
    }
}

// ---- aggregation: out_i = relu( d_i * sum_j d_j * t_j  + d_i^2 * t_i + b ) -
// one wave per node; 64 lanes x float2 = 128 cols

__global__ __launch_bounds__(256) void agg_kernel(
        const float* __restrict__ t, const int* __restrict__ rowptr,
        const int* __restrict__ col, const float* __restrict__ dinv,
        const float* __restrict__ bias, float* __restrict__ out, int n) {
    int node = blockIdx.x * 4 + (threadIdx.x >> 6);
    int lane = threadIdx.x & 63;
    if (node >= n) return;
    float di = dinv[node];
    const float2* tn = (const float2*)(t + (size_t)node * 128);
    float2 ts = tn[lane];
    float sw = di * di;                       // self-loop weight
    float2 acc; acc.x = sw * ts.x; acc.y = sw * ts.y;
    int beg = rowptr[node], end = rowptr[node + 1];
    for (int base = beg; base < end; base += 64) {
        int m  = end - base; if (m > 64) m = 64;
        int jv   = (lane < m) ? col[base + lane] : 0;
        float dv = (lane < m) ? dinv[jv] : 0.0f;
        for (int e = 0; e < m; ++e) {
            int   j  = __shfl(jv, e);
            float dj = __shfl(dv, e);
            const float2* tj = (const float2*)(t + (size_t)j * 128);
            float2 v = tj[lane];
            float w = di * dj;
            acc.x += w * v.x; acc.y += w * v.y;
        }
    }
    const float2* b2 = (const float2*)bias;
    float2 bb = b2[lane];
    acc.x = fmaxf(acc.x + bb.x, 0.0f);
    acc.y = fmaxf(acc.y + bb.y, 0.0f);
    ((float2*)(out + (size_t)node * 128))[lane] = acc;
}

// ---- dense 128x128 GEMM: out = A @ W (+bias, relu) ------------------------
// block: 256 threads, 64 rows x 128 cols; thread = 8 rows x 4 cols

template <bool BIAS_RELU>
__global__ __launch_bounds__(256) void gemm128_kernel(
        const float* __restrict__ A, const float* __restrict__ W,
        const float* __restrict__ bias, float* __restrict__ out, int n) {
    __shared__ float As[64 * 128];   // 32 KB
    __shared__ float Ws[16 * 128];   //  8 KB
    int tid  = threadIdx.x;
    int row0 = blockIdx.x * 64;
    int rows = n - row0; if (rows > 64) rows = 64;

    // load A tile (contiguous chunk of A)
    const float4* A4  = (const float4*)(A + (size_t)row0 * 128);
    float4*       As4 = (float4*)As;
    int n4 = rows * 32;
    for (int idx = tid; idx < n4; idx += 256) As4[idx] = A4[idx];

    float acc[8][4];
    #pragma unroll
    for (int r = 0; r < 8; ++r)
        #pragma unroll
        for (int c = 0; c < 4; ++c) acc[r][c] = 0.0f;

    int tx = tid & 31, ty = tid >> 5;

    for (int kc = 0; kc < 8; ++kc) {
        __syncthreads();
        const float4* W4  = (const float4*)(W + kc * 16 * 128);
        float4*       Ws4 = (float4*)Ws;
        for (int idx = tid; idx < 512; idx += 256) Ws4[idx] = W4[idx];
        __syncthreads();
        #pragma unroll
        for (int k = 0; k < 16; ++k) {
            float4 w4 = ((const float4*)(Ws + k * 128))[tx];
            #pragma unroll
            for (int r = 0; r < 8; ++r) {
                float a = As[(ty * 8 + r) * 128 + kc * 16 + k];
                acc[r][0] += a * w4.x; acc[r][1] += a * w4.y;
                acc[r][2] += a * w4.z; acc[r][3] += a * w4.w;
            }
        }
    }

    float4 bb = make_float4(0.f, 0.f, 0.f, 0.f);
    if (BIAS_RELU) bb = ((const float4*)bias)[tx];
    #pragma unroll
    for (int r = 0; r < 8; ++r) {
        int row = ty * 8 + r;
        if (row < rows) {
            float4 v;
            v.x = acc[r][0]; v.y = acc[r][1]; v.z = acc[r][2]; v.w = acc[r][3];
            if (BIAS_RELU) {
                v.x = fmaxf(v.x + bb.x, 0.f); v.y = fmaxf(v.y + bb.y, 0.f);
                v.z = fmaxf(v.z + bb.z, 0.f); v.w = fmaxf(v.w + bb.w, 0.f);
            }
            ((float4*)(out + (size_t)(row0 + row) * 128))[tx] = v;
        }
    }
}

// ---- output layer: out = h @ W_ed + b_ed + x  (128 -> 3) ------------------
// one wave per node; each lane holds 2 of the 128 k's, shuffle-reduce 3 sums

__global__ __launch_bounds__(256) void out_kernel(
        const float* __restrict__ h, const float* __restrict__ W,
        const float* __restrict__ bias, const float* __restrict__ x,
        float* __restrict__ out, int n) {
    int node = blockIdx.x * 4 + (threadIdx.x >> 6);
    int lane = threadIdx.x & 63;
    if (node >= n) return;
    float h0 = h[(size_t)node * 128 + lane];
    float h1 = h[(size_t)node * 128 + 64 + lane];
    float s0 = h0 * W[lane*3+0] + h1 * W[(lane+64)*3+0];
    float s1 = h0 * W[lane*3+1] + h1 * W[(lane+64)*3+1];
    float s2 = h0 * W[lane*3+2] + h1 * W[(lane+64)*3+2];
    #pragma unroll
    for (int off = 32; off > 0; off >>= 1) {
        s0 += __shfl_down(s0, off);
        s1 += __shfl_down(s1, off);
        s2 += __shfl_down(s2, off);
    }
    if (lane == 0) {
        out[node*3+0] = s0 + bias[0] + x[node*3+0];
        out[node*3+1] = s1 + bias[1] + x[node*3+1];
        out[node*3+2] = s2 + bias[2] + x[node*3+2];
    }
}

// ---------------------------------------------------------------------------

extern "C" void kernel_launch(void* const* d_in, const int* in_sizes, int n_in,
                              void* d_out, int out_size, void* d_ws, size_t ws_size,
                              hipStream_t stream) {
    const float* x    = (const float*)d_in[0];
    const int*   ei   = (const int*)d_in[1];
    const float* W_s  = (const float*)d_in[2];
    const float* b_s  = (const float*)d_in[3];
    const float* W_m  = (const float*)d_in[4];
    const float* b_m  = (const float*)d_in[5];
    const float* W_e  = (const float*)d_in[6];
    const float* b_e  = (const float*)d_in[7];
    const float* W_sd = (const float*)d_in[8];
    const float* b_sd = (const float*)d_in[9];
    const float* W_md = (const float*)d_in[10];
    const float* b_md = (const float*)d_in[11];
    const float* W_ed = (const float*)d_in[12];
    const float* b_ed = (const float*)d_in[13];
    float* outp = (float*)d_out;

    const int N = in_sizes[0] / 3;
    const int E = in_sizes[1] / 2;
    const int* src = ei;
    const int* dst = ei + E;

    // workspace carve (256B aligned)
    char* p = (char*)d_ws;
    auto carve = [&](size_t bytes) {
        void* r = (void*)p;
        p += (bytes + 255) & ~(size_t)255;
        return r;
    };
    int*   counts  = (int*)  carve((size_t)N * 4);
    int*   rowptr  = (int*)  carve((size_t)(N + 1) * 4);
    int*   fillcur = (int*)  carve((size_t)N * 4);
    int*   col     = (int*)  carve((size_t)E * 4);
    float* dinv    = (float*)carve((size_t)N * 4);
    float* A       = (float*)carve((size_t)N * 128 * 4);
    float* B       = (float*)carve((size_t)N * 128 * 4);
    (void)ws_size;

    const int gE = (E + 255) / 256;
    const int gN = (N + 255) / 256;
    const int gNode4 = (N + 3) / 4;      // wave-per-node kernels
    const int gRow64 = (N + 63) / 64;    // gemm128 blocks

    // graph build
    hipMemsetAsync(counts, 0, (size_t)N * 4, stream);
    count_kernel<<<gE, 256, 0, stream>>>(dst, counts, E);
    scan_kernel<<<1, 1024, 0, stream>>>(counts, rowptr, fillcur, N, E);
    fill_kernel<<<gE, 256, 0, stream>>>(src, dst, fillcur, col, E);
    dinv_kernel<<<gN, 256, 0, stream>>>(counts, dinv, N);

    // encoder
    in_gemm_kernel<<<(N * 128 + 255) / 256, 256, 0, stream>>>(x, W_s, B, N);
    agg_kernel<<<gNode4, 256, 0, stream>>>(B, rowptr, col, dinv, b_s, A, N);

    gemm128_kernel<false><<<gRow64, 256, 0, stream>>>(A, W_m, nullptr, B, N);
    agg_kernel<<<gNode4, 256, 0, stream>>>(B, rowptr, col, dinv, b_m, A, N);

    gemm128_kernel<false><<<gRow64, 256, 0, stream>>>(A, W_m, nullptr, B, N);
    agg_kernel<<<gNode4, 256, 0, stream>>>(B, rowptr, col, dinv, b_m, A, N);

    gemm128_kernel<false><<<gRow64, 256, 0, stream>>>(A, W_e, nullptr, B, N);
    agg_kernel<<<gNode4, 256, 0, stream>>>(B, rowptr, col, dinv, b_e, A, N);

    // decoder
    gemm128_kernel<true><<<gRow64, 256, 0, stream>>>(A, W_sd, b_sd, B, N);
    gemm128_kernel<true><<<gRow64, 256, 0, stream>>>(B, W_md, b_md, A, N);
    gemm128_kernel<true><<<gRow64, 256, 0, stream>>>(A, W_md, b_md, B, N);
    out_kernel<<<gNode4, 256, 0, stream>>>(B, W_ed, b_ed, x, outp, N);
}

// Round 2
// 858.752 us; speedup vs baseline: 1.4834x; 1.4834x over previous
//
#include <hip/hip_runtime.h>

// ---------------------------------------------------------------------------
// GCN encoder (4 conv layers, shared CSR graph) + 3-layer MLP decoder.
// Round 2: bf16 activations + MFMA GEMMs, dinv folded into GEMM epilogue,
// parallel scan. Graph build (count/scan/fill) unchanged from round 1.
// ---------------------------------------------------------------------------

typedef __attribute__((ext_vector_type(8))) short short8;
typedef __attribute__((ext_vector_type(4))) float floatx4;

__device__ __forceinline__ unsigned short f2bf(float f) {
    unsigned int u = __float_as_uint(f);
    u += 0x7fffu + ((u >> 16) & 1u);          // round-to-nearest-even
    return (unsigned short)(u >> 16);
}
__device__ __forceinline__ float2 bfx2(unsigned int u) {
    float2 r;
    r.x = __uint_as_float(u << 16);
    r.y = __uint_as_float(u & 0xffff0000u);
    return r;
}

// ---- graph build ----------------------------------------------------------

__global__ void count_kernel(const int* __restrict__ dst, int* __restrict__ counts, int E) {
    int e = blockIdx.x * 256 + threadIdx.x;
    if (e < E) atomicAdd(&counts[dst[e]], 1);
}

// phase 1: per-block exclusive scan (4096 elems/block) + block totals
__global__ __launch_bounds__(1024) void scan1_kernel(const int* __restrict__ counts,
        int* __restrict__ rowptr, int* __restrict__ partials, int n) {
    __shared__ int wsum[16];
    int tid = threadIdx.x, lane = tid & 63, wid = tid >> 6;
    int i0 = blockIdx.x * 4096 + tid * 4;
    int c[4];
    #pragma unroll
    for (int k = 0; k < 4; ++k) c[k] = (i0 + k < n) ? counts[i0 + k] : 0;
    int tot = c[0] + c[1] + c[2] + c[3];
    int s = tot;
    #pragma unroll
    for (int off = 1; off < 64; off <<= 1) {
        int u = __shfl_up(s, off);
        if (lane >= off) s += u;
    }
    if (lane == 63) wsum[wid] = s;
    __syncthreads();
    int woff = 0;
    #pragma unroll
    for (int w = 0; w < 16; ++w)
        if (w < wid) woff += wsum[w];
    int run = woff + s - tot;
    #pragma unroll
    for (int k = 0; k < 4; ++k) {
        if (i0 + k < n) rowptr[i0 + k] = run;
        run += c[k];
    }
    if (tid == 0) {
        int bt = 0;
        #pragma unroll
        for (int w = 0; w < 16; ++w) bt += wsum[w];
        partials[blockIdx.x] = bt;
    }
}

// phase 2: add block offsets, mirror into fillcur, terminate rowptr
__global__ __launch_bounds__(1024) void scan2_kernel(int* __restrict__ rowptr,
        int* __restrict__ fillcur, const int* __restrict__ partials, int n, int e_total) {
    __shared__ int offs;
    int tid = threadIdx.x;
    if (tid == 0) {
        int s = 0;
        for (int w = 0; w < (int)blockIdx.x; ++w) s += partials[w];
        offs = s;
    }
    __syncthreads();
    int off = offs;
    int i0 = blockIdx.x * 4096 + tid * 4;
    #pragma unroll
    for (int k = 0; k < 4; ++k) {
        int i = i0 + k;
        if (i < n) { int v = rowptr[i] + off; rowptr[i] = v; fillcur[i] = v; }
    }
    if (blockIdx.x == 0 && tid == 0) rowptr[n] = e_total;
}

__global__ void fill_kernel(const int* __restrict__ src, const int* __restrict__ dst,
                            int* __restrict__ fillcur, int* __restrict__ col, int E) {
    int e = blockIdx.x * 256 + threadIdx.x;
    if (e < E) {
        int pos = atomicAdd(&fillcur[dst[e]], 1);
        col[pos] = src[e];
    }
}

__global__ void dinv_kernel(const int* __restrict__ counts, float* __restrict__ dinv, int n) {
    int i = blockIdx.x * 256 + threadIdx.x;
    if (i < n) dinv[i] = 1.0f / sqrtf((float)(counts[i] + 1));   // +1 self loop
}

// ---- weight pre-pack into MFMA B-fragment order ---------------------------
// pack[((kc*8+nt)*64+lane)*8+j] = bf16( W[kc*32+(lane>>4)*8+j][nt*16+(lane&15)] )

__global__ void pack_kernel(const float* __restrict__ W0, const float* __restrict__ W1,
                            const float* __restrict__ W2, const float* __restrict__ W3,
                            unsigned short* __restrict__ P0, unsigned short* __restrict__ P1,
                            unsigned short* __restrict__ P2, unsigned short* __restrict__ P3) {
    int which = blockIdx.x >> 3;
    const float* W = which == 0 ? W0 : which == 1 ? W1 : which == 2 ? W2 : W3;
    unsigned short* P = which == 0 ? P0 : which == 1 ? P1 : which == 2 ? P2 : P3;
    int f = (blockIdx.x & 7) * 256 + threadIdx.x;   // fragment id 0..2047
    int lane = f & 63, nt = (f >> 6) & 7, kc = f >> 9;
    int kbase = kc * 32 + (lane >> 4) * 8;
    int ncol = nt * 16 + (lane & 15);
    short8 frag;
    #pragma unroll
    for (int j = 0; j < 8; ++j)
        frag[j] = (short)f2bf(W[(size_t)(kbase + j) * 128 + ncol]);
    *((short8*)(P + (size_t)f * 8)) = frag;
}

// ---- input layer: t' = dinv_i * (x @ W_s)  (N x 3 @ 3 x 128) --------------

__global__ void in_gemm_kernel(const float* __restrict__ x, const float* __restrict__ W,
                               const float* __restrict__ dinv,
                               unsigned short* __restrict__ t, int n) {
    int g = blockIdx.x * 256 + threadIdx.x;
    int i = g >> 6, c2 = g & 63;
    if (i >= n) return;
    float x0 = x[i * 3], x1 = x[i * 3 + 1], x2 = x[i * 3 + 2];
    float d = dinv[i];
    int c = c2 * 2;
    float v0 = d * (x0 * W[c]     + x1 * W[128 + c]     + x2 * W[256 + c]);
    float v1 = d * (x0 * W[c + 1] + x1 * W[128 + c + 1] + x2 * W[256 + c + 1]);
    unsigned int o = (unsigned int)f2bf(v0) | ((unsigned int)f2bf(v1) << 16);
    ((unsigned int*)t)[(size_t)i * 64 + c2] = o;
}

// ---- aggregation: out_i = relu( d_i * (t'_i + sum_j t'_j) + b ) -----------
// t' rows already carry d_j. One wave per node; lane = 2 cols (bf16x2).

__global__ __launch_bounds__(256) void agg_kernel(
        const unsigned short* __restrict__ t, const int* __restrict__ rowptr,
        const int* __restrict__ col, const float* __restrict__ dinv,
        const float* __restrict__ bias, unsigned short* __restrict__ out, int n) {
    int node = blockIdx.x * 4 + (threadIdx.x >> 6);
    int lane = threadIdx.x & 63;
    if (node >= n) return;
    float2 acc = bfx2(((const unsigned int*)(t + (size_t)node * 128))[lane]);  // self
    int beg = rowptr[node], end = rowptr[node + 1];
    for (int base = beg; base < end; base += 64) {
        int m = end - base; if (m > 64) m = 64;
        int jv = (lane < m) ? col[base + lane] : 0;
        for (int e = 0; e < m; ++e) {
            int j = __shfl(jv, e);
            float2 v = bfx2(((const unsigned int*)(t + (size_t)j * 128))[lane]);
            acc.x += v.x; acc.y += v.y;
        }
    }
    float di = dinv[node];
    float2 bb = ((const float2*)bias)[lane];
    float ox = fmaxf(di * acc.x + bb.x, 0.f);
    float oy = fmaxf(di * acc.y + bb.y, 0.f);
    unsigned int o = (unsigned int)f2bf(ox) | ((unsigned int)f2bf(oy) << 16);
    ((unsigned int*)(out + (size_t)node * 128))[lane] = o;
}

// ---- dense 128x128 GEMM via MFMA 16x16x32 bf16 ----------------------------
// 256 thr = 4 waves; wave w -> rows [blk*64 + w*16, +16), all 128 cols.
// SCALE_DINV: out = dinv[row] * (A@W)      (encoder, feeds next agg)
// BIAS_RELU : out = relu(A@W + bias)       (decoder)

template <bool SCALE_DINV, bool BIAS_RELU>
__global__ __launch_bounds__(256) void gemm_mfma_kernel(
        const unsigned short* __restrict__ A, const unsigned short* __restrict__ Wp,
        const float* __restrict__ bias, const float* __restrict__ dinv,
        unsigned short* __restrict__ out, int n) {
    __shared__ unsigned short Ws[16384];   // 32 KB packed weights
    int tid = threadIdx.x;
    {
        const int4* s = (const int4*)Wp;
        int4* d = (int4*)Ws;
        #pragma unroll
        for (int i = 0; i < 8; ++i) d[tid + 256 * i] = s[tid + 256 * i];
    }
    int wave = tid >> 6, lane = tid & 63;
    int quad = lane >> 4, mrow = lane & 15;
    int row0 = blockIdx.x * 64 + wave * 16;
    __syncthreads();

    int arow = row0 + mrow; if (arow >= n) arow = n - 1;
    const unsigned short* abase = A + (size_t)arow * 128 + quad * 8;
    short8 af[4];
    #pragma unroll
    for (int kc = 0; kc < 4; ++kc)
        af[kc] = *((const short8*)(abase + kc * 32));

    floatx4 acc[8];
    #pragma unroll
    for (int t = 0; t < 8; ++t) acc[t] = (floatx4){0.f, 0.f, 0.f, 0.f};

    #pragma unroll
    for (int kc = 0; kc < 4; ++kc) {
        #pragma unroll
        for (int nt = 0; nt < 8; ++nt) {
            short8 bf = *((const short8*)(Ws + ((kc * 8 + nt) * 64 + lane) * 8));
            acc[nt] = __builtin_amdgcn_mfma_f32_16x16x32_bf16(af[kc], bf, acc[nt], 0, 0, 0);
        }
    }

    float dv[4];
    if (SCALE_DINV) {
        #pragma unroll
        for (int r = 0; r < 4; ++r) {
            int row = row0 + quad * 4 + r;
            dv[r] = (row < n) ? dinv[row] : 0.f;
        }
    }
    #pragma unroll
    for (int nt = 0; nt < 8; ++nt) {
        int colc = nt * 16 + mrow;
        float bcol = BIAS_RELU ? bias[colc] : 0.f;
        #pragma unroll
        for (int r = 0; r < 4; ++r) {
            int row = row0 + quad * 4 + r;
            if (row < n) {
                float v = acc[nt][r];
                if (BIAS_RELU) v = fmaxf(v + bcol, 0.f);
                if (SCALE_DINV) v *= dv[r];
                out[(size_t)row * 128 + colc] = f2bf(v);
            }
        }
    }
}

// ---- output layer: out = h @ W_ed + b_ed + x  (128 -> 3) ------------------

__global__ __launch_bounds__(256) void out_kernel(
        const unsigned short* __restrict__ h, const float* __restrict__ W,
        const float* __restrict__ bias, const float* __restrict__ x,
        float* __restrict__ out, int n) {
    int node = blockIdx.x * 4 + (threadIdx.x >> 6);
    int lane = threadIdx.x & 63;
    if (node >= n) return;
    float2 hv = bfx2(((const unsigned int*)(h + (size_t)node * 128))[lane]);
    int c = lane * 2;
    float s0 = hv.x * W[c * 3]     + hv.y * W[(c + 1) * 3];
    float s1 = hv.x * W[c * 3 + 1] + hv.y * W[(c + 1) * 3 + 1];
    float s2 = hv.x * W[c * 3 + 2] + hv.y * W[(c + 1) * 3 + 2];
    #pragma unroll
    for (int off = 32; off > 0; off >>= 1) {
        s0 += __shfl_down(s0, off);
        s1 += __shfl_down(s1, off);
        s2 += __shfl_down(s2, off);
    }
    if (lane == 0) {
        out[node * 3 + 0] = s0 + bias[0] + x[node * 3 + 0];
        out[node * 3 + 1] = s1 + bias[1] + x[node * 3 + 1];
        out[node * 3 + 2] = s2 + bias[2] + x[node * 3 + 2];
    }
}

// ---------------------------------------------------------------------------

extern "C" void kernel_launch(void* const* d_in, const int* in_sizes, int n_in,
                              void* d_out, int out_size, void* d_ws, size_t ws_size,
                              hipStream_t stream) {
    const float* x    = (const float*)d_in[0];
    const int*   ei   = (const int*)d_in[1];
    const float* W_s  = (const float*)d_in[2];
    const float* b_s  = (const float*)d_in[3];
    const float* W_m  = (const float*)d_in[4];
    const float* b_m  = (const float*)d_in[5];
    const float* W_e  = (const float*)d_in[6];
    const float* b_e  = (const float*)d_in[7];
    const float* W_sd = (const float*)d_in[8];
    const float* b_sd = (const float*)d_in[9];
    const float* W_md = (const float*)d_in[10];
    const float* b_md = (const float*)d_in[11];
    const float* W_ed = (const float*)d_in[12];
    const float* b_ed = (const float*)d_in[13];
    float* outp = (float*)d_out;

    const int N = in_sizes[0] / 3;
    const int E = in_sizes[1] / 2;
    const int* src = ei;
    const int* dst = ei + E;

    char* p = (char*)d_ws;
    auto carve = [&](size_t bytes) {
        void* r = (void*)p;
        p += (bytes + 255) & ~(size_t)255;
        return r;
    };
    int*   counts   = (int*)  carve((size_t)N * 4);
    int*   rowptr   = (int*)  carve((size_t)(N + 1) * 4);
    int*   fillcur  = (int*)  carve((size_t)N * 4);
    int*   col      = (int*)  carve((size_t)E * 4);
    float* dinv     = (float*)carve((size_t)N * 4);
    int*   partials = (int*)  carve(64 * 4);
    unsigned short* Wp_m  = (unsigned short*)carve(16384 * 2);
    unsigned short* Wp_e  = (unsigned short*)carve(16384 * 2);
    unsigned short* Wp_sd = (unsigned short*)carve(16384 * 2);
    unsigned short* Wp_md = (unsigned short*)carve(16384 * 2);
    unsigned short* A = (unsigned short*)carve((size_t)N * 128 * 2);
    unsigned short* B = (unsigned short*)carve((size_t)N * 128 * 2);
    (void)ws_size;

    const int gE = (E + 255) / 256;
    const int gN = (N + 255) / 256;
    const int gScan = (N + 4095) / 4096;
    const int gNode4 = (N + 3) / 4;
    const int gRow64 = (N + 63) / 64;

    // graph build
    hipMemsetAsync(counts, 0, (size_t)N * 4, stream);
    count_kernel<<<gE, 256, 0, stream>>>(dst, counts, E);
    scan1_kernel<<<gScan, 1024, 0, stream>>>(counts, rowptr, partials, N);
    scan2_kernel<<<gScan, 1024, 0, stream>>>(rowptr, fillcur, partials, N, E);
    fill_kernel<<<gE, 256, 0, stream>>>(src, dst, fillcur, col, E);
    dinv_kernel<<<gN, 256, 0, stream>>>(counts, dinv, N);

    // weight packs
    pack_kernel<<<32, 256, 0, stream>>>(W_m, W_e, W_sd, W_md, Wp_m, Wp_e, Wp_sd, Wp_md);

    // encoder
    in_gemm_kernel<<<(N * 64 + 255) / 256, 256, 0, stream>>>(x, W_s, dinv, B, N);
    agg_kernel<<<gNode4, 256, 0, stream>>>(B, rowptr, col, dinv, b_s, A, N);

    gemm_mfma_kernel<true, false><<<gRow64, 256, 0, stream>>>(A, Wp_m, nullptr, dinv, B, N);
    agg_kernel<<<gNode4, 256, 0, stream>>>(B, rowptr, col, dinv, b_m, A, N);

    gemm_mfma_kernel<true, false><<<gRow64, 256, 0, stream>>>(A, Wp_m, nullptr, dinv, B, N);
    agg_kernel<<<gNode4, 256, 0, stream>>>(B, rowptr, col, dinv, b_m, A, N);

    gemm_mfma_kernel<true, false><<<gRow64, 256, 0, stream>>>(A, Wp_e, nullptr, dinv, B, N);
    agg_kernel<<<gNode4, 256, 0, stream>>>(B, rowptr, col, dinv, b_e, A, N);

    // decoder
    gemm_mfma_kernel<false, true><<<gRow64, 256, 0, stream>>>(A, Wp_sd, b_sd, nullptr, B, N);
    gemm_mfma_kernel<false, true><<<gRow64, 256, 0, stream>>>(B, Wp_md, b_md, nullptr, A, N);
    gemm_mfma_kernel<false, true><<<gRow64, 256, 0, stream>>>(A, Wp_md, b_md, nullptr, B, N);
    out_kernel<<<gNode4, 256, 0, stream>>>(B, W_ed, b_ed, x, outp, N);
}

// Round 3
// 679.726 us; speedup vs baseline: 1.8741x; 1.2634x over previous
//
#include <hip/hip_runtime.h>

// ---------------------------------------------------------------------------
// GCN encoder (4 conv layers, shared CSR graph) + 3-layer MLP decoder.
// Round 3: agg_kernel edge loop batched 8-deep (8 row-gathers in flight per
// wave instead of 1) — attacks the latency-bound aggregation.
// ---------------------------------------------------------------------------

typedef __attribute__((ext_vector_type(8))) short short8;
typedef __attribute__((ext_vector_type(4))) float floatx4;

__device__ __forceinline__ unsigned short f2bf(float f) {
    unsigned int u = __float_as_uint(f);
    u += 0x7fffu + ((u >> 16) & 1u);          // round-to-nearest-even
    return (unsigned short)(u >> 16);
}
__device__ __forceinline__ float2 bfx2(unsigned int u) {
    float2 r;
    r.x = __uint_as_float(u << 16);
    r.y = __uint_as_float(u & 0xffff0000u);
    return r;
}

// ---- graph build ----------------------------------------------------------

__global__ void count_kernel(const int* __restrict__ dst, int* __restrict__ counts, int E) {
    int e = blockIdx.x * 256 + threadIdx.x;
    if (e < E) atomicAdd(&counts[dst[e]], 1);
}

// phase 1: per-block exclusive scan (4096 elems/block) + block totals
__global__ __launch_bounds__(1024) void scan1_kernel(const int* __restrict__ counts,
        int* __restrict__ rowptr, int* __restrict__ partials, int n) {
    __shared__ int wsum[16];
    int tid = threadIdx.x, lane = tid & 63, wid = tid >> 6;
    int i0 = blockIdx.x * 4096 + tid * 4;
    int c[4];
    #pragma unroll
    for (int k = 0; k < 4; ++k) c[k] = (i0 + k < n) ? counts[i0 + k] : 0;
    int tot = c[0] + c[1] + c[2] + c[3];
    int s = tot;
    #pragma unroll
    for (int off = 1; off < 64; off <<= 1) {
        int u = __shfl_up(s, off);
        if (lane >= off) s += u;
    }
    if (lane == 63) wsum[wid] = s;
    __syncthreads();
    int woff = 0;
    #pragma unroll
    for (int w = 0; w < 16; ++w)
        if (w < wid) woff += wsum[w];
    int run = woff + s - tot;
    #pragma unroll
    for (int k = 0; k < 4; ++k) {
        if (i0 + k < n) rowptr[i0 + k] = run;
        run += c[k];
    }
    if (tid == 0) {
        int bt = 0;
        #pragma unroll
        for (int w = 0; w < 16; ++w) bt += wsum[w];
        partials[blockIdx.x] = bt;
    }
}

// phase 2: add block offsets, mirror into fillcur, terminate rowptr
__global__ __launch_bounds__(1024) void scan2_kernel(int* __restrict__ rowptr,
        int* __restrict__ fillcur, const int* __restrict__ partials, int n, int e_total) {
    __shared__ int offs;
    int tid = threadIdx.x;
    if (tid == 0) {
        int s = 0;
        for (int w = 0; w < (int)blockIdx.x; ++w) s += partials[w];
        offs = s;
    }
    __syncthreads();
    int off = offs;
    int i0 = blockIdx.x * 4096 + tid * 4;
    #pragma unroll
    for (int k = 0; k < 4; ++k) {
        int i = i0 + k;
        if (i < n) { int v = rowptr[i] + off; rowptr[i] = v; fillcur[i] = v; }
    }
    if (blockIdx.x == 0 && tid == 0) rowptr[n] = e_total;
}

__global__ void fill_kernel(const int* __restrict__ src, const int* __restrict__ dst,
                            int* __restrict__ fillcur, int* __restrict__ col, int E) {
    int e = blockIdx.x * 256 + threadIdx.x;
    if (e < E) {
        int pos = atomicAdd(&fillcur[dst[e]], 1);
        col[pos] = src[e];
    }
}

__global__ void dinv_kernel(const int* __restrict__ counts, float* __restrict__ dinv, int n) {
    int i = blockIdx.x * 256 + threadIdx.x;
    if (i < n) dinv[i] = 1.0f / sqrtf((float)(counts[i] + 1));   // +1 self loop
}

// ---- weight pre-pack into MFMA B-fragment order ---------------------------

__global__ void pack_kernel(const float* __restrict__ W0, const float* __restrict__ W1,
                            const float* __restrict__ W2, const float* __restrict__ W3,
                            unsigned short* __restrict__ P0, unsigned short* __restrict__ P1,
                            unsigned short* __restrict__ P2, unsigned short* __restrict__ P3) {
    int which = blockIdx.x >> 3;
    const float* W = which == 0 ? W0 : which == 1 ? W1 : which == 2 ? W2 : W3;
    unsigned short* P = which == 0 ? P0 : which == 1 ? P1 : which == 2 ? P2 : P3;
    int f = (blockIdx.x & 7) * 256 + threadIdx.x;   // fragment id 0..2047
    int lane = f & 63, nt = (f >> 6) & 7, kc = f >> 9;
    int kbase = kc * 32 + (lane >> 4) * 8;
    int ncol = nt * 16 + (lane & 15);
    short8 frag;
    #pragma unroll
    for (int j = 0; j < 8; ++j)
        frag[j] = (short)f2bf(W[(size_t)(kbase + j) * 128 + ncol]);
    *((short8*)(P + (size_t)f * 8)) = frag;
}

// ---- input layer: t' = dinv_i * (x @ W_s)  (N x 3 @ 3 x 128) --------------

__global__ void in_gemm_kernel(const float* __restrict__ x, const float* __restrict__ W,
                               const float* __restrict__ dinv,
                               unsigned short* __restrict__ t, int n) {
    int g = blockIdx.x * 256 + threadIdx.x;
    int i = g >> 6, c2 = g & 63;
    if (i >= n) return;
    float x0 = x[i * 3], x1 = x[i * 3 + 1], x2 = x[i * 3 + 2];
    float d = dinv[i];
    int c = c2 * 2;
    float v0 = d * (x0 * W[c]     + x1 * W[128 + c]     + x2 * W[256 + c]);
    float v1 = d * (x0 * W[c + 1] + x1 * W[128 + c + 1] + x2 * W[256 + c + 1]);
    unsigned int o = (unsigned int)f2bf(v0) | ((unsigned int)f2bf(v1) << 16);
    ((unsigned int*)t)[(size_t)i * 64 + c2] = o;
}

// ---- aggregation: out_i = relu( d_i * (t'_i + sum_j t'_j) + b ) -----------
// t' rows already carry d_j. One wave per node; lane = 2 cols (bf16x2).
// Edge loop batched 8-deep: 8 independent row loads in flight per wave.

__global__ __launch_bounds__(256) void agg_kernel(
        const unsigned short* __restrict__ t, const int* __restrict__ rowptr,
        const int* __restrict__ col, const float* __restrict__ dinv,
        const float* __restrict__ bias, unsigned short* __restrict__ out, int n) {
    int node = blockIdx.x * 4 + (threadIdx.x >> 6);
    int lane = threadIdx.x & 63;
    if (node >= n) return;
    float2 acc = bfx2(((const unsigned int*)(t + (size_t)node * 128))[lane]);  // self
    int beg = rowptr[node], end = rowptr[node + 1];
    int deg = end - beg;
    for (int base = 0; base < deg; base += 64) {
        int m = deg - base; if (m > 64) m = 64;
        // out-of-range lanes point at the node's own (cache-hot) row; their
        // loaded values are masked to bf16 zero below.
        int jv = (lane < m) ? col[beg + base + lane] : node;
        for (int e = 0; e < m; e += 8) {
            unsigned int v[8];
            #pragma unroll
            for (int q = 0; q < 8; ++q) {
                int j = __shfl(jv, e + q);
                v[q] = ((const unsigned int*)(t + (size_t)j * 128))[lane];
            }
            #pragma unroll
            for (int q = 0; q < 8; ++q) {
                unsigned int u = (e + q < m) ? v[q] : 0u;   // bf16 0|0 == 0.0f
                float2 f = bfx2(u);
                acc.x += f.x; acc.y += f.y;
            }
        }
    }
    float di = dinv[node];
    float2 bb = ((const float2*)bias)[lane];
    float ox = fmaxf(di * acc.x + bb.x, 0.f);
    float oy = fmaxf(di * acc.y + bb.y, 0.f);
    unsigned int o = (unsigned int)f2bf(ox) | ((unsigned int)f2bf(oy) << 16);
    ((unsigned int*)(out + (size_t)node * 128))[lane] = o;
}

// ---- dense 128x128 GEMM via MFMA 16x16x32 bf16 ----------------------------
// 256 thr = 4 waves; wave w -> rows [blk*64 + w*16, +16), all 128 cols.
// SCALE_DINV: out = dinv[row] * (A@W)      (encoder, feeds next agg)
// BIAS_RELU : out = relu(A@W + bias)       (decoder)

template <bool SCALE_DINV, bool BIAS_RELU>
__global__ __launch_bounds__(256) void gemm_mfma_kernel(
        const unsigned short* __restrict__ A, const unsigned short* __restrict__ Wp,
        const float* __restrict__ bias, const float* __restrict__ dinv,
        unsigned short* __restrict__ out, int n) {
    __shared__ unsigned short Ws[16384];   // 32 KB packed weights
    int tid = threadIdx.x;
    {
        const int4* s = (const int4*)Wp;
        int4* d = (int4*)Ws;
        #pragma unroll
        for (int i = 0; i < 8; ++i) d[tid + 256 * i] = s[tid + 256 * i];
    }
    int wave = tid >> 6, lane = tid & 63;
    int quad = lane >> 4, mrow = lane & 15;
    int row0 = blockIdx.x * 64 + wave * 16;
    __syncthreads();

    int arow = row0 + mrow; if (arow >= n) arow = n - 1;
    const unsigned short* abase = A + (size_t)arow * 128 + quad * 8;
    short8 af[4];
    #pragma unroll
    for (int kc = 0; kc < 4; ++kc)
        af[kc] = *((const short8*)(abase + kc * 32));

    floatx4 acc[8];
    #pragma unroll
    for (int t = 0; t < 8; ++t) acc[t] = (floatx4){0.f, 0.f, 0.f, 0.f};

    #pragma unroll
    for (int kc = 0; kc < 4; ++kc) {
        #pragma unroll
        for (int nt = 0; nt < 8; ++nt) {
            short8 bf = *((const short8*)(Ws + ((kc * 8 + nt) * 64 + lane) * 8));
            acc[nt] = __builtin_amdgcn_mfma_f32_16x16x32_bf16(af[kc], bf, acc[nt], 0, 0, 0);
        }
    }

    float dv[4];
    if (SCALE_DINV) {
        #pragma unroll
        for (int r = 0; r < 4; ++r) {
            int row = row0 + quad * 4 + r;
            dv[r] = (row < n) ? dinv[row] : 0.f;
        }
    }
    #pragma unroll
    for (int nt = 0; nt < 8; ++nt) {
        int colc = nt * 16 + mrow;
        float bcol = BIAS_RELU ? bias[colc] : 0.f;
        #pragma unroll
        for (int r = 0; r < 4; ++r) {
            int row = row0 + quad * 4 + r;
            if (row < n) {
                float v = acc[nt][r];
                if (BIAS_RELU) v = fmaxf(v + bcol, 0.f);
                if (SCALE_DINV) v *= dv[r];
                out[(size_t)row * 128 + colc] = f2bf(v);
            }
        }
    }
}

// ---- output layer: out = h @ W_ed + b_ed + x  (128 -> 3) ------------------

__global__ __launch_bounds__(256) void out_kernel(
        const unsigned short* __restrict__ h, const float* __restrict__ W,
        const float* __restrict__ bias, const float* __restrict__ x,
        float* __restrict__ out, int n) {
    int node = blockIdx.x * 4 + (threadIdx.x >> 6);
    int lane = threadIdx.x & 63;
    if (node >= n) return;
    float2 hv = bfx2(((const unsigned int*)(h + (size_t)node * 128))[lane]);
    int c = lane * 2;
    float s0 = hv.x * W[c * 3]     + hv.y * W[(c + 1) * 3];
    float s1 = hv.x * W[c * 3 + 1] + hv.y * W[(c + 1) * 3 + 1];
    float s2 = hv.x * W[c * 3 + 2] + hv.y * W[(c + 1) * 3 + 2];
    #pragma unroll
    for (int off = 32; off > 0; off >>= 1) {
        s0 += __shfl_down(s0, off);
        s1 += __shfl_down(s1, off);
        s2 += __shfl_down(s2, off);
    }
    if (lane == 0) {
        out[node * 3 + 0] = s0 + bias[0] + x[node * 3 + 0];
        out[node * 3 + 1] = s1 + bias[1] + x[node * 3 + 1];
        out[node * 3 + 2] = s2 + bias[2] + x[node * 3 + 2];
    }
}

// ---------------------------------------------------------------------------

extern "C" void kernel_launch(void* const* d_in, const int* in_sizes, int n_in,
                              void* d_out, int out_size, void* d_ws, size_t ws_size,
                              hipStream_t stream) {
    const float* x    = (const float*)d_in[0];
    const int*   ei   = (const int*)d_in[1];
    const float* W_s  = (const float*)d_in[2];
    const float* b_s  = (const float*)d_in[3];
    const float* W_m  = (const float*)d_in[4];
    const float* b_m  = (const float*)d_in[5];
    const float* W_e  = (const float*)d_in[6];
    const float* b_e  = (const float*)d_in[7];
    const float* W_sd = (const float*)d_in[8];
    const float* b_sd = (const float*)d_in[9];
    const float* W_md = (const float*)d_in[10];
    const float* b_md = (const float*)d_in[11];
    const float* W_ed = (const float*)d_in[12];
    const float* b_ed = (const float*)d_in[13];
    float* outp = (float*)d_out;

    const int N = in_sizes[0] / 3;
    const int E = in_sizes[1] / 2;
    const int* src = ei;
    const int* dst = ei + E;

    char* p = (char*)d_ws;
    auto carve = [&](size_t bytes) {
        void* r = (void*)p;
        p += (bytes + 255) & ~(size_t)255;
        return r;
    };
    int*   counts   = (int*)  carve((size_t)N * 4);
    int*   rowptr   = (int*)  carve((size_t)(N + 1) * 4);
    int*   fillcur  = (int*)  carve((size_t)N * 4);
    int*   col      = (int*)  carve((size_t)E * 4);
    float* dinv     = (float*)carve((size_t)N * 4);
    int*   partials = (int*)  carve(64 * 4);
    unsigned short* Wp_m  = (unsigned short*)carve(16384 * 2);
    unsigned short* Wp_e  = (unsigned short*)carve(16384 * 2);
    unsigned short* Wp_sd = (unsigned short*)carve(16384 * 2);
    unsigned short* Wp_md = (unsigned short*)carve(16384 * 2);
    unsigned short* A = (unsigned short*)carve((size_t)N * 128 * 2);
    unsigned short* B = (unsigned short*)carve((size_t)N * 128 * 2);
    (void)ws_size;

    const int gE = (E + 255) / 256;
    const int gN = (N + 255) / 256;
    const int gScan = (N + 4095) / 4096;
    const int gNode4 = (N + 3) / 4;
    const int gRow64 = (N + 63) / 64;

    // graph build
    hipMemsetAsync(counts, 0, (size_t)N * 4, stream);
    count_kernel<<<gE, 256, 0, stream>>>(dst, counts, E);
    scan1_kernel<<<gScan, 1024, 0, stream>>>(counts, rowptr, partials, N);
    scan2_kernel<<<gScan, 1024, 0, stream>>>(rowptr, fillcur, partials, N, E);
    fill_kernel<<<gE, 256, 0, stream>>>(src, dst, fillcur, col, E);
    dinv_kernel<<<gN, 256, 0, stream>>>(counts, dinv, N);

    // weight packs
    pack_kernel<<<32, 256, 0, stream>>>(W_m, W_e, W_sd, W_md, Wp_m, Wp_e, Wp_sd, Wp_md);

    // encoder
    in_gemm_kernel<<<(N * 64 + 255) / 256, 256, 0, stream>>>(x, W_s, dinv, B, N);
    agg_kernel<<<gNode4, 256, 0, stream>>>(B, rowptr, col, dinv, b_s, A, N);

    gemm_mfma_kernel<true, false><<<gRow64, 256, 0, stream>>>(A, Wp_m, nullptr, dinv, B, N);
    agg_kernel<<<gNode4, 256, 0, stream>>>(B, rowptr, col, dinv, b_m, A, N);

    gemm_mfma_kernel<true, false><<<gRow64, 256, 0, stream>>>(A, Wp_m, nullptr, dinv, B, N);
    agg_kernel<<<gNode4, 256, 0, stream>>>(B, rowptr, col, dinv, b_m, A, N);

    gemm_mfma_kernel<true, false><<<gRow64, 256, 0, stream>>>(A, Wp_e, nullptr, dinv, B, N);
    agg_kernel<<<gNode4, 256, 0, stream>>>(B, rowptr, col, dinv, b_e, A, N);

    // decoder
    gemm_mfma_kernel<false, true><<<gRow64, 256, 0, stream>>>(A, Wp_sd, b_sd, nullptr, B, N);
    gemm_mfma_kernel<false, true><<<gRow64, 256, 0, stream>>>(B, Wp_md, b_md, nullptr, A, N);
    gemm_mfma_kernel<false, true><<<gRow64, 256, 0, stream>>>(A, Wp_md, b_md, nullptr, B, N);
    out_kernel<<<gNode4, 256, 0, stream>>>(B, W_ed, b_ed, x, outp, N);
}

// Round 4
// 587.465 us; speedup vs baseline: 2.1685x; 1.1570x over previous
//
#include <hip/hip_runtime.h>

// ---------------------------------------------------------------------------
// GCN encoder (4 conv layers, shared CSR graph) + 3-layer MLP decoder.
// Round 4: graph build rewritten as bucketed counting sort (XCD-local
// writes, no random global atomics) — replaces count/fill/dinv kernels.
// ---------------------------------------------------------------------------

typedef __attribute__((ext_vector_type(8))) short short8;
typedef __attribute__((ext_vector_type(4))) float floatx4;

__device__ __forceinline__ unsigned short f2bf(float f) {
    unsigned int u = __float_as_uint(f);
    u += 0x7fffu + ((u >> 16) & 1u);          // round-to-nearest-even
    return (unsigned short)(u >> 16);
}
__device__ __forceinline__ float2 bfx2(unsigned int u) {
    float2 r;
    r.x = __uint_as_float(u << 16);
    r.y = __uint_as_float(u & 0xffff0000u);
    return r;
}

// ---- graph build: bucketed counting sort ----------------------------------
// buckets of 128 dst-nodes; 8 groups (blockIdx&7 ~ XCD) so each append
// stream is XCD-local. entry = (local<<24) | src   (src < 2^24).

__global__ void bin_kernel(const int* __restrict__ src, const int* __restrict__ dst,
                           int* __restrict__ bfill, unsigned int* __restrict__ binbuf,
                           int B, int C, int E) {
    int e = blockIdx.x * 256 + threadIdx.x;
    if (e >= E) return;
    int d = dst[e];
    int b = d >> 7;
    int g = blockIdx.x & 7;
    int slot = atomicAdd(&bfill[g * B + b], 1);
    if (slot < C)
        binbuf[(size_t)(g * B + b) * C + slot] = (unsigned int)src[e] | ((unsigned int)(d & 127) << 24);
}

// one block per bucket: LDS histogram -> counts + dinv (coalesced writes)
__global__ __launch_bounds__(256) void hist_kernel(
        const unsigned int* __restrict__ binbuf, const int* __restrict__ bfill,
        int* __restrict__ counts, float* __restrict__ dinv, int B, int C, int n) {
    __shared__ int h[128];
    int b = blockIdx.x, t = threadIdx.x;
    if (t < 128) h[t] = 0;
    __syncthreads();
    #pragma unroll
    for (int g = 0; g < 8; ++g) {
        int cnt = bfill[g * B + b];
        const unsigned int* p = binbuf + (size_t)(g * B + b) * C;
        for (int i = t; i < cnt; i += 256)
            atomicAdd(&h[p[i] >> 24], 1);
    }
    __syncthreads();
    int node = b * 128 + t;
    if (t < 128 && node < n) {
        counts[node] = h[t];
        dinv[node] = 1.0f / sqrtf((float)(h[t] + 1));   // +1 self loop
    }
}

// phase 1: per-block exclusive scan (4096 elems/block) + block totals
__global__ __launch_bounds__(1024) void scan1_kernel(const int* __restrict__ counts,
        int* __restrict__ rowptr, int* __restrict__ partials, int n) {
    __shared__ int wsum[16];
    int tid = threadIdx.x, lane = tid & 63, wid = tid >> 6;
    int i0 = blockIdx.x * 4096 + tid * 4;
    int c[4];
    #pragma unroll
    for (int k = 0; k < 4; ++k) c[k] = (i0 + k < n) ? counts[i0 + k] : 0;
    int tot = c[0] + c[1] + c[2] + c[3];
    int s = tot;
    #pragma unroll
    for (int off = 1; off < 64; off <<= 1) {
        int u = __shfl_up(s, off);
        if (lane >= off) s += u;
    }
    if (lane == 63) wsum[wid] = s;
    __syncthreads();
    int woff = 0;
    #pragma unroll
    for (int w = 0; w < 16; ++w)
        if (w < wid) woff += wsum[w];
    int run = woff + s - tot;
    #pragma unroll
    for (int k = 0; k < 4; ++k) {
        if (i0 + k < n) rowptr[i0 + k] = run;
        run += c[k];
    }
    if (tid == 0) {
        int bt = 0;
        #pragma unroll
        for (int w = 0; w < 16; ++w) bt += wsum[w];
        partials[blockIdx.x] = bt;
    }
}

// phase 2: add block offsets, terminate rowptr
__global__ __launch_bounds__(1024) void scan2_kernel(int* __restrict__ rowptr,
        const int* __restrict__ partials, int n, int e_total) {
    __shared__ int offs;
    int tid = threadIdx.x;
    if (tid == 0) {
        int s = 0;
        for (int w = 0; w < (int)blockIdx.x; ++w) s += partials[w];
        offs = s;
    }
    __syncthreads();
    int off = offs;
    int i0 = blockIdx.x * 4096 + tid * 4;
    #pragma unroll
    for (int k = 0; k < 4; ++k) {
        int i = i0 + k;
        if (i < n) rowptr[i] += off;
    }
    if (blockIdx.x == 0 && tid == 0) rowptr[n] = e_total;
}

// one block per bucket: scatter col within the bucket's (L2-local) region
__global__ __launch_bounds__(256) void place_kernel(
        const unsigned int* __restrict__ binbuf, const int* __restrict__ bfill,
        const int* __restrict__ rowptr, int* __restrict__ col, int B, int C, int n) {
    __shared__ int cur[128];
    int b = blockIdx.x, t = threadIdx.x;
    int node = b * 128 + t;
    if (t < 128) cur[t] = (node < n) ? rowptr[node] : 0;
    __syncthreads();
    #pragma unroll
    for (int g = 0; g < 8; ++g) {
        int cnt = bfill[g * B + b];
        const unsigned int* p = binbuf + (size_t)(g * B + b) * C;
        for (int i = t; i < cnt; i += 256) {
            unsigned int e = p[i];
            int pos = atomicAdd(&cur[e >> 24], 1);
            col[pos] = (int)(e & 0xFFFFFFu);
        }
    }
}

// ---- weight pre-pack into MFMA B-fragment order ---------------------------

__global__ void pack_kernel(const float* __restrict__ W0, const float* __restrict__ W1,
                            const float* __restrict__ W2, const float* __restrict__ W3,
                            unsigned short* __restrict__ P0, unsigned short* __restrict__ P1,
                            unsigned short* __restrict__ P2, unsigned short* __restrict__ P3) {
    int which = blockIdx.x >> 3;
    const float* W = which == 0 ? W0 : which == 1 ? W1 : which == 2 ? W2 : W3;
    unsigned short* P = which == 0 ? P0 : which == 1 ? P1 : which == 2 ? P2 : P3;
    int f = (blockIdx.x & 7) * 256 + threadIdx.x;   // fragment id 0..2047
    int lane = f & 63, nt = (f >> 6) & 7, kc = f >> 9;
    int kbase = kc * 32 + (lane >> 4) * 8;
    int ncol = nt * 16 + (lane & 15);
    short8 frag;
    #pragma unroll
    for (int j = 0; j < 8; ++j)
        frag[j] = (short)f2bf(W[(size_t)(kbase + j) * 128 + ncol]);
    *((short8*)(P + (size_t)f * 8)) = frag;
}

// ---- input layer: t' = dinv_i * (x @ W_s)  (N x 3 @ 3 x 128) --------------

__global__ void in_gemm_kernel(const float* __restrict__ x, const float* __restrict__ W,
                               const float* __restrict__ dinv,
                               unsigned short* __restrict__ t, int n) {
    int g = blockIdx.x * 256 + threadIdx.x;
    int i = g >> 6, c2 = g & 63;
    if (i >= n) return;
    float x0 = x[i * 3], x1 = x[i * 3 + 1], x2 = x[i * 3 + 2];
    float d = dinv[i];
    int c = c2 * 2;
    float v0 = d * (x0 * W[c]     + x1 * W[128 + c]     + x2 * W[256 + c]);
    float v1 = d * (x0 * W[c + 1] + x1 * W[128 + c + 1] + x2 * W[256 + c + 1]);
    unsigned int o = (unsigned int)f2bf(v0) | ((unsigned int)f2bf(v1) << 16);
    ((unsigned int*)t)[(size_t)i * 64 + c2] = o;
}

// ---- aggregation: out_i = relu( d_i * (t'_i + sum_j t'_j) + b ) -----------
// t' rows already carry d_j. One wave per node; lane = 2 cols (bf16x2).
// Edge loop batched 8-deep: 8 independent row loads in flight per wave.

__global__ __launch_bounds__(256) void agg_kernel(
        const unsigned short* __restrict__ t, const int* __restrict__ rowptr,
        const int* __restrict__ col, const float* __restrict__ dinv,
        const float* __restrict__ bias, unsigned short* __restrict__ out, int n) {
    int node = blockIdx.x * 4 + (threadIdx.x >> 6);
    int lane = threadIdx.x & 63;
    if (node >= n) return;
    float2 acc = bfx2(((const unsigned int*)(t + (size_t)node * 128))[lane]);  // self
    int beg = rowptr[node], end = rowptr[node + 1];
    int deg = end - beg;
    for (int base = 0; base < deg; base += 64) {
        int m = deg - base; if (m > 64) m = 64;
        int jv = (lane < m) ? col[beg + base + lane] : node;
        for (int e = 0; e < m; e += 8) {
            unsigned int v[8];
            #pragma unroll
            for (int q = 0; q < 8; ++q) {
                int j = __shfl(jv, e + q);
                v[q] = ((const unsigned int*)(t + (size_t)j * 128))[lane];
            }
            #pragma unroll
            for (int q = 0; q < 8; ++q) {
                unsigned int u = (e + q < m) ? v[q] : 0u;   // bf16 0|0 == 0.0f
                float2 f = bfx2(u);
                acc.x += f.x; acc.y += f.y;
            }
        }
    }
    float di = dinv[node];
    float2 bb = ((const float2*)bias)[lane];
    float ox = fmaxf(di * acc.x + bb.x, 0.f);
    float oy = fmaxf(di * acc.y + bb.y, 0.f);
    unsigned int o = (unsigned int)f2bf(ox) | ((unsigned int)f2bf(oy) << 16);
    ((unsigned int*)(out + (size_t)node * 128))[lane] = o;
}

// ---- dense 128x128 GEMM via MFMA 16x16x32 bf16 ----------------------------

template <bool SCALE_DINV, bool BIAS_RELU>
__global__ __launch_bounds__(256) void gemm_mfma_kernel(
        const unsigned short* __restrict__ A, const unsigned short* __restrict__ Wp,
        const float* __restrict__ bias, const float* __restrict__ dinv,
        unsigned short* __restrict__ out, int n) {
    __shared__ unsigned short Ws[16384];   // 32 KB packed weights
    int tid = threadIdx.x;
    {
        const int4* s = (const int4*)Wp;
        int4* d = (int4*)Ws;
        #pragma unroll
        for (int i = 0; i < 8; ++i) d[tid + 256 * i] = s[tid + 256 * i];
    }
    int wave = tid >> 6, lane = tid & 63;
    int quad = lane >> 4, mrow = lane & 15;
    int row0 = blockIdx.x * 64 + wave * 16;
    __syncthreads();

    int arow = row0 + mrow; if (arow >= n) arow = n - 1;
    const unsigned short* abase = A + (size_t)arow * 128 + quad * 8;
    short8 af[4];
    #pragma unroll
    for (int kc = 0; kc < 4; ++kc)
        af[kc] = *((const short8*)(abase + kc * 32));

    floatx4 acc[8];
    #pragma unroll
    for (int t = 0; t < 8; ++t) acc[t] = (floatx4){0.f, 0.f, 0.f, 0.f};

    #pragma unroll
    for (int kc = 0; kc < 4; ++kc) {
        #pragma unroll
        for (int nt = 0; nt < 8; ++nt) {
            short8 bf = *((const short8*)(Ws + ((kc * 8 + nt) * 64 + lane) * 8));
            acc[nt] = __builtin_amdgcn_mfma_f32_16x16x32_bf16(af[kc], bf, acc[nt], 0, 0, 0);
        }
    }

    float dv[4];
    if (SCALE_DINV) {
        #pragma unroll
        for (int r = 0; r < 4; ++r) {
            int row = row0 + quad * 4 + r;
            dv[r] = (row < n) ? dinv[row] : 0.f;
        }
    }
    #pragma unroll
    for (int nt = 0; nt < 8; ++nt) {
        int colc = nt * 16 + mrow;
        float bcol = BIAS_RELU ? bias[colc] : 0.f;
        #pragma unroll
        for (int r = 0; r < 4; ++r) {
            int row = row0 + quad * 4 + r;
            if (row < n) {
                float v = acc[nt][r];
                if (BIAS_RELU) v = fmaxf(v + bcol, 0.f);
                if (SCALE_DINV) v *= dv[r];
                out[(size_t)row * 128 + colc] = f2bf(v);
            }
        }
    }
}

// ---- output layer: out = h @ W_ed + b_ed + x  (128 -> 3) ------------------

__global__ __launch_bounds__(256) void out_kernel(
        const unsigned short* __restrict__ h, const float* __restrict__ W,
        const float* __restrict__ bias, const float* __restrict__ x,
        float* __restrict__ out, int n) {
    int node = blockIdx.x * 4 + (threadIdx.x >> 6);
    int lane = threadIdx.x & 63;
    if (node >= n) return;
    float2 hv = bfx2(((const unsigned int*)(h + (size_t)node * 128))[lane]);
    int c = lane * 2;
    float s0 = hv.x * W[c * 3]     + hv.y * W[(c + 1) * 3];
    float s1 = hv.x * W[c * 3 + 1] + hv.y * W[(c + 1) * 3 + 1];
    float s2 = hv.x * W[c * 3 + 2] + hv.y * W[(c + 1) * 3 + 2];
    #pragma unroll
    for (int off = 32; off > 0; off >>= 1) {
        s0 += __shfl_down(s0, off);
        s1 += __shfl_down(s1, off);
        s2 += __shfl_down(s2, off);
    }
    if (lane == 0) {
        out[node * 3 + 0] = s0 + bias[0] + x[node * 3 + 0];
        out[node * 3 + 1] = s1 + bias[1] + x[node * 3 + 1];
        out[node * 3 + 2] = s2 + bias[2] + x[node * 3 + 2];
    }
}

// ---------------------------------------------------------------------------

extern "C" void kernel_launch(void* const* d_in, const int* in_sizes, int n_in,
                              void* d_out, int out_size, void* d_ws, size_t ws_size,
                              hipStream_t stream) {
    const float* x    = (const float*)d_in[0];
    const int*   ei   = (const int*)d_in[1];
    const float* W_s  = (const float*)d_in[2];
    const float* b_s  = (const float*)d_in[3];
    const float* W_m  = (const float*)d_in[4];
    const float* b_m  = (const float*)d_in[5];
    const float* W_e  = (const float*)d_in[6];
    const float* b_e  = (const float*)d_in[7];
    const float* W_sd = (const float*)d_in[8];
    const float* b_sd = (const float*)d_in[9];
    const float* W_md = (const float*)d_in[10];
    const float* b_md = (const float*)d_in[11];
    const float* W_ed = (const float*)d_in[12];
    const float* b_ed = (const float*)d_in[13];
    float* outp = (float*)d_out;

    const int N = in_sizes[0] / 3;
    const int E = in_sizes[1] / 2;
    const int* src = ei;
    const int* dst = ei + E;

    const int B = (N + 127) >> 7;                        // 128-node buckets
    const int C = ((E / (B * 8)) * 2 + 63) & ~63;        // per-(group,bucket) cap

    char* p = (char*)d_ws;
    auto carve = [&](size_t bytes) {
        void* r = (void*)p;
        p += (bytes + 255) & ~(size_t)255;
        return r;
    };
    int*   counts   = (int*)  carve((size_t)N * 4);
    int*   rowptr   = (int*)  carve((size_t)(N + 1) * 4);
    int*   col      = (int*)  carve((size_t)E * 4);
    float* dinv     = (float*)carve((size_t)N * 4);
    int*   partials = (int*)  carve(64 * 4);
    int*   bfill    = (int*)  carve((size_t)8 * B * 4);
    unsigned int* binbuf = (unsigned int*)carve((size_t)8 * B * C * 4);
    unsigned short* Wp_m  = (unsigned short*)carve(16384 * 2);
    unsigned short* Wp_e  = (unsigned short*)carve(16384 * 2);
    unsigned short* Wp_sd = (unsigned short*)carve(16384 * 2);
    unsigned short* Wp_md = (unsigned short*)carve(16384 * 2);
    unsigned short* A = (unsigned short*)carve((size_t)N * 128 * 2);
    unsigned short* Bm = (unsigned short*)carve((size_t)N * 128 * 2);
    (void)ws_size;

    const int gE = (E + 255) / 256;
    const int gScan = (N + 4095) / 4096;
    const int gNode4 = (N + 3) / 4;
    const int gRow64 = (N + 63) / 64;

    // graph build (bucketed counting sort)
    hipMemsetAsync(bfill, 0, (size_t)8 * B * 4, stream);
    bin_kernel<<<gE, 256, 0, stream>>>(src, dst, bfill, binbuf, B, C, E);
    hist_kernel<<<B, 256, 0, stream>>>(binbuf, bfill, counts, dinv, B, C, N);
    scan1_kernel<<<gScan, 1024, 0, stream>>>(counts, rowptr, partials, N);
    scan2_kernel<<<gScan, 1024, 0, stream>>>(rowptr, partials, N, E);
    place_kernel<<<B, 256, 0, stream>>>(binbuf, bfill, rowptr, col, B, C, N);

    // weight packs
    pack_kernel<<<32, 256, 0, stream>>>(W_m, W_e, W_sd, W_md, Wp_m, Wp_e, Wp_sd, Wp_md);

    // encoder
    in_gemm_kernel<<<(N * 64 + 255) / 256, 256, 0, stream>>>(x, W_s, dinv, Bm, N);
    agg_kernel<<<gNode4, 256, 0, stream>>>(Bm, rowptr, col, dinv, b_s, A, N);

    gemm_mfma_kernel<true, false><<<gRow64, 256, 0, stream>>>(A, Wp_m, nullptr, dinv, Bm, N);
    agg_kernel<<<gNode4, 256, 0, stream>>>(Bm, rowptr, col, dinv, b_m, A, N);

    gemm_mfma_kernel<true, false><<<gRow64, 256, 0, stream>>>(A, Wp_m, nullptr, dinv, Bm, N);
    agg_kernel<<<gNode4, 256, 0, stream>>>(Bm, rowptr, col, dinv, b_m, A, N);

    gemm_mfma_kernel<true, false><<<gRow64, 256, 0, stream>>>(A, Wp_e, nullptr, dinv, Bm, N);
    agg_kernel<<<gNode4, 256, 0, stream>>>(Bm, rowptr, col, dinv, b_e, A, N);

    // decoder
    gemm_mfma_kernel<false, true><<<gRow64, 256, 0, stream>>>(A, Wp_sd, b_sd, nullptr, Bm, N);
    gemm_mfma_kernel<false, true><<<gRow64, 256, 0, stream>>>(Bm, Wp_md, b_md, nullptr, A, N);
    gemm_mfma_kernel<false, true><<<gRow64, 256, 0, stream>>>(A, Wp_md, b_md, nullptr, Bm, N);
    out_kernel<<<gNode4, 256, 0, stream>>>(Bm, W_ed, b_ed, x, outp, N);
}

// Round 5
// 519.829 us; speedup vs baseline: 2.4506x; 1.1301x over previous
//
#include <hip/hip_runtime.h>

// ---------------------------------------------------------------------------
// GCN encoder (4 conv layers, shared CSR graph) + 3-layer MLP decoder.
// Round 5: graph build v3 — block-aggregated binning (one global atomic per
// block-bucket, dense run writes) + fused per-bucket hist/scan/place.
// Buckets: 512 dst-nodes (d>>9); entry = (d&511)<<17 | src  (src < 2^17).
// ---------------------------------------------------------------------------

typedef __attribute__((ext_vector_type(8))) short short8;
typedef __attribute__((ext_vector_type(4))) float floatx4;

#define BIN_CH 8192          // edges per bin block
#define NBMAX 512            // max buckets supported

__device__ __forceinline__ unsigned short f2bf(float f) {
    unsigned int u = __float_as_uint(f);
    u += 0x7fffu + ((u >> 16) & 1u);          // round-to-nearest-even
    return (unsigned short)(u >> 16);
}
__device__ __forceinline__ float2 bfx2(unsigned int u) {
    float2 r;
    r.x = __uint_as_float(u << 16);
    r.y = __uint_as_float(u & 0xffff0000u);
    return r;
}

// ---- graph build ----------------------------------------------------------

// block-aggregated binning: LDS hist -> local scan -> 1 global atomic per
// (block,bucket) run reservation -> dense run writes into bucket segments.
__global__ __launch_bounds__(512) void bin_kernel(
        const int* __restrict__ src, const int* __restrict__ dst,
        int* __restrict__ gfill, unsigned int* __restrict__ binbuf,
        int NB, int C, int E) {
    __shared__ int hist[NBMAX];
    __shared__ int start[NBMAX];
    __shared__ int dstoff[NBMAX];
    int tid = threadIdx.x;
    int e0 = blockIdx.x * BIN_CH;
    for (int i = tid; i < NB; i += 512) hist[i] = 0;
    __syncthreads();
    for (int i = tid; i < BIN_CH; i += 512) {
        int e = e0 + i;
        if (e < E) atomicAdd(&hist[dst[e] >> 9], 1);
    }
    __syncthreads();
    if (tid < 64) {                       // wave 0: exclusive scan hist->start
        int carry = 0;
        for (int base = 0; base < NB; base += 64) {
            int idx = base + tid;
            int v = (idx < NB) ? hist[idx] : 0;
            int s = v;
            #pragma unroll
            for (int off = 1; off < 64; off <<= 1) {
                int u = __shfl_up(s, off);
                if (tid >= off) s += u;
            }
            if (idx < NB) start[idx] = carry + s - v;
            carry += __shfl(s, 63);
        }
    }
    __syncthreads();
    for (int i = tid; i < NB; i += 512) { // reserve global runs
        int cnt = hist[i];
        int g = cnt ? atomicAdd(&gfill[i], cnt) : 0;
        dstoff[i] = g - start[i];
        hist[i] = start[i];               // reuse as local cursor
    }
    __syncthreads();
    for (int i = tid; i < BIN_CH; i += 512) {
        int e = e0 + i;
        if (e >= E) continue;
        int d = dst[e];
        int b = d >> 9;
        int slot = atomicAdd(&hist[b], 1);            // local rank
        int gidx = b * C + dstoff[b] + slot;
        if (gidx < (b + 1) * C)
            binbuf[gidx] = (unsigned int)src[e] | ((unsigned int)(d & 511) << 17);
    }
}

// exclusive scan over NB bucket sizes (1 wave)
__global__ void bscan_kernel(const int* __restrict__ gfill, int* __restrict__ bbase, int NB) {
    int lane = threadIdx.x;
    int carry = 0;
    for (int base = 0; base < NB; base += 64) {
        int idx = base + lane;
        int v = (idx < NB) ? gfill[idx] : 0;
        int s = v;
        #pragma unroll
        for (int off = 1; off < 64; off <<= 1) {
            int u = __shfl_up(s, off);
            if (lane >= off) s += u;
        }
        if (idx < NB) bbase[idx] = carry + s - v;
        carry += __shfl(s, 63);
    }
}

// one block per bucket: hist(512) -> scan -> rowptr/dinv -> place col
__global__ __launch_bounds__(256) void build_kernel(
        const unsigned int* __restrict__ binbuf, const int* __restrict__ gfill,
        const int* __restrict__ bbase, int* __restrict__ rowptr,
        float* __restrict__ dinv, int* __restrict__ col,
        int NB, int C, int N, int E) {
    __shared__ int h[512];
    __shared__ int hs[512];
    int b = blockIdx.x, tid = threadIdx.x;
    int cnt = gfill[b];
    const unsigned int* p = binbuf + (size_t)b * C;
    for (int i = tid; i < 512; i += 256) h[i] = 0;
    __syncthreads();
    for (int i = tid; i < cnt; i += 256) atomicAdd(&h[p[i] >> 17], 1);
    __syncthreads();
    if (tid < 64) {                       // wave 0: exclusive scan h->hs
        int carry = 0;
        for (int base = 0; base < 512; base += 64) {
            int v = h[base + tid];
            int s = v;
            #pragma unroll
            for (int off = 1; off < 64; off <<= 1) {
                int u = __shfl_up(s, off);
                if (tid >= off) s += u;
            }
            hs[base + tid] = carry + s - v;
            carry += __shfl(s, 63);
        }
    }
    __syncthreads();
    int base = bbase[b];
    for (int i = tid; i < 512; i += 256) {
        int node = b * 512 + i;
        if (node < N) {
            rowptr[node] = base + hs[i];
            dinv[node] = 1.0f / sqrtf((float)(h[i] + 1));   // +1 self loop
        }
    }
    if (b == 0 && tid == 0) rowptr[N] = E;
    __syncthreads();
    for (int i = tid; i < cnt; i += 256) {  // place (hs doubles as cursor)
        unsigned int u = p[i];
        int local = u >> 17;
        int pos = atomicAdd(&hs[local], 1);
        col[base + pos] = (int)(u & 0x1FFFFu);
    }
}

// ---- weight pre-pack into MFMA B-fragment order ---------------------------

__global__ void pack_kernel(const float* __restrict__ W0, const float* __restrict__ W1,
                            const float* __restrict__ W2, const float* __restrict__ W3,
                            unsigned short* __restrict__ P0, unsigned short* __restrict__ P1,
                            unsigned short* __restrict__ P2, unsigned short* __restrict__ P3) {
    int which = blockIdx.x >> 3;
    const float* W = which == 0 ? W0 : which == 1 ? W1 : which == 2 ? W2 : W3;
    unsigned short* P = which == 0 ? P0 : which == 1 ? P1 : which == 2 ? P2 : P3;
    int f = (blockIdx.x & 7) * 256 + threadIdx.x;   // fragment id 0..2047
    int lane = f & 63, nt = (f >> 6) & 7, kc = f >> 9;
    int kbase = kc * 32 + (lane >> 4) * 8;
    int ncol = nt * 16 + (lane & 15);
    short8 frag;
    #pragma unroll
    for (int j = 0; j < 8; ++j)
        frag[j] = (short)f2bf(W[(size_t)(kbase + j) * 128 + ncol]);
    *((short8*)(P + (size_t)f * 8)) = frag;
}

// ---- input layer: t' = dinv_i * (x @ W_s)  (N x 3 @ 3 x 128) --------------

__global__ void in_gemm_kernel(const float* __restrict__ x, const float* __restrict__ W,
                               const float* __restrict__ dinv,
                               unsigned short* __restrict__ t, int n) {
    int g = blockIdx.x * 256 + threadIdx.x;
    int i = g >> 6, c2 = g & 63;
    if (i >= n) return;
    float x0 = x[i * 3], x1 = x[i * 3 + 1], x2 = x[i * 3 + 2];
    float d = dinv[i];
    int c = c2 * 2;
    float v0 = d * (x0 * W[c]     + x1 * W[128 + c]     + x2 * W[256 + c]);
    float v1 = d * (x0 * W[c + 1] + x1 * W[128 + c + 1] + x2 * W[256 + c + 1]);
    unsigned int o = (unsigned int)f2bf(v0) | ((unsigned int)f2bf(v1) << 16);
    ((unsigned int*)t)[(size_t)i * 64 + c2] = o;
}

// ---- aggregation: out_i = relu( d_i * (t'_i + sum_j t'_j) + b ) -----------
// t' rows already carry d_j. One wave per node; lane = 2 cols (bf16x2).
// Edge loop batched 8-deep: 8 independent row loads in flight per wave.

__global__ __launch_bounds__(256) void agg_kernel(
        const unsigned short* __restrict__ t, const int* __restrict__ rowptr,
        const int* __restrict__ col, const float* __restrict__ dinv,
        const float* __restrict__ bias, unsigned short* __restrict__ out, int n) {
    int node = blockIdx.x * 4 + (threadIdx.x >> 6);
    int lane = threadIdx.x & 63;
    if (node >= n) return;
    float2 acc = bfx2(((const unsigned int*)(t + (size_t)node * 128))[lane]);  // self
    int beg = rowptr[node], end = rowptr[node + 1];
    int deg = end - beg;
    for (int base = 0; base < deg; base += 64) {
        int m = deg - base; if (m > 64) m = 64;
        int jv = (lane < m) ? col[beg + base + lane] : node;
        for (int e = 0; e < m; e += 8) {
            unsigned int v[8];
            #pragma unroll
            for (int q = 0; q < 8; ++q) {
                int j = __shfl(jv, e + q);
                v[q] = ((const unsigned int*)(t + (size_t)j * 128))[lane];
            }
            #pragma unroll
            for (int q = 0; q < 8; ++q) {
                unsigned int u = (e + q < m) ? v[q] : 0u;   // bf16 0|0 == 0.0f
                float2 f = bfx2(u);
                acc.x += f.x; acc.y += f.y;
            }
        }
    }
    float di = dinv[node];
    float2 bb = ((const float2*)bias)[lane];
    float ox = fmaxf(di * acc.x + bb.x, 0.f);
    float oy = fmaxf(di * acc.y + bb.y, 0.f);
    unsigned int o = (unsigned int)f2bf(ox) | ((unsigned int)f2bf(oy) << 16);
    ((unsigned int*)(out + (size_t)node * 128))[lane] = o;
}

// ---- dense 128x128 GEMM via MFMA 16x16x32 bf16 ----------------------------

template <bool SCALE_DINV, bool BIAS_RELU>
__global__ __launch_bounds__(256) void gemm_mfma_kernel(
        const unsigned short* __restrict__ A, const unsigned short* __restrict__ Wp,
        const float* __restrict__ bias, const float* __restrict__ dinv,
        unsigned short* __restrict__ out, int n) {
    __shared__ unsigned short Ws[16384];   // 32 KB packed weights
    int tid = threadIdx.x;
    {
        const int4* s = (const int4*)Wp;
        int4* d = (int4*)Ws;
        #pragma unroll
        for (int i = 0; i < 8; ++i) d[tid + 256 * i] = s[tid + 256 * i];
    }
    int wave = tid >> 6, lane = tid & 63;
    int quad = lane >> 4, mrow = lane & 15;
    int row0 = blockIdx.x * 64 + wave * 16;
    __syncthreads();

    int arow = row0 + mrow; if (arow >= n) arow = n - 1;
    const unsigned short* abase = A + (size_t)arow * 128 + quad * 8;
    short8 af[4];
    #pragma unroll
    for (int kc = 0; kc < 4; ++kc)
        af[kc] = *((const short8*)(abase + kc * 32));

    floatx4 acc[8];
    #pragma unroll
    for (int t = 0; t < 8; ++t) acc[t] = (floatx4){0.f, 0.f, 0.f, 0.f};

    #pragma unroll
    for (int kc = 0; kc < 4; ++kc) {
        #pragma unroll
        for (int nt = 0; nt < 8; ++nt) {
            short8 bf = *((const short8*)(Ws + ((kc * 8 + nt) * 64 + lane) * 8));
            acc[nt] = __builtin_amdgcn_mfma_f32_16x16x32_bf16(af[kc], bf, acc[nt], 0, 0, 0);
        }
    }

    float dv[4];
    if (SCALE_DINV) {
        #pragma unroll
        for (int r = 0; r < 4; ++r) {
            int row = row0 + quad * 4 + r;
            dv[r] = (row < n) ? dinv[row] : 0.f;
        }
    }
    #pragma unroll
    for (int nt = 0; nt < 8; ++nt) {
        int colc = nt * 16 + mrow;
        float bcol = BIAS_RELU ? bias[colc] : 0.f;
        #pragma unroll
        for (int r = 0; r < 4; ++r) {
            int row = row0 + quad * 4 + r;
            if (row < n) {
                float v = acc[nt][r];
                if (BIAS_RELU) v = fmaxf(v + bcol, 0.f);
                if (SCALE_DINV) v *= dv[r];
                out[(size_t)row * 128 + colc] = f2bf(v);
            }
        }
    }
}

// ---- output layer: out = h @ W_ed + b_ed + x  (128 -> 3) ------------------

__global__ __launch_bounds__(256) void out_kernel(
        const unsigned short* __restrict__ h, const float* __restrict__ W,
        const float* __restrict__ bias, const float* __restrict__ x,
        float* __restrict__ out, int n) {
    int node = blockIdx.x * 4 + (threadIdx.x >> 6);
    int lane = threadIdx.x & 63;
    if (node >= n) return;
    float2 hv = bfx2(((const unsigned int*)(h + (size_t)node * 128))[lane]);
    int c = lane * 2;
    float s0 = hv.x * W[c * 3]     + hv.y * W[(c + 1) * 3];
    float s1 = hv.x * W[c * 3 + 1] + hv.y * W[(c + 1) * 3 + 1];
    float s2 = hv.x * W[c * 3 + 2] + hv.y * W[(c + 1) * 3 + 2];
    #pragma unroll
    for (int off = 32; off > 0; off >>= 1) {
        s0 += __shfl_down(s0, off);
        s1 += __shfl_down(s1, off);
        s2 += __shfl_down(s2, off);
    }
    if (lane == 0) {
        out[node * 3 + 0] = s0 + bias[0] + x[node * 3 + 0];
        out[node * 3 + 1] = s1 + bias[1] + x[node * 3 + 1];
        out[node * 3 + 2] = s2 + bias[2] + x[node * 3 + 2];
    }
}

// ---------------------------------------------------------------------------

extern "C" void kernel_launch(void* const* d_in, const int* in_sizes, int n_in,
                              void* d_out, int out_size, void* d_ws, size_t ws_size,
                              hipStream_t stream) {
    const float* x    = (const float*)d_in[0];
    const int*   ei   = (const int*)d_in[1];
    const float* W_s  = (const float*)d_in[2];
    const float* b_s  = (const float*)d_in[3];
    const float* W_m  = (const float*)d_in[4];
    const float* b_m  = (const float*)d_in[5];
    const float* W_e  = (const float*)d_in[6];
    const float* b_e  = (const float*)d_in[7];
    const float* W_sd = (const float*)d_in[8];
    const float* b_sd = (const float*)d_in[9];
    const float* W_md = (const float*)d_in[10];
    const float* b_md = (const float*)d_in[11];
    const float* W_ed = (const float*)d_in[12];
    const float* b_ed = (const float*)d_in[13];
    float* outp = (float*)d_out;

    const int N = in_sizes[0] / 3;
    const int E = in_sizes[1] / 2;
    const int* src = ei;
    const int* dst = ei + E;

    const int NB = (N + 511) >> 9;                 // 512-node buckets
    const int C  = (((E / NB) * 3 / 2) + 255) & ~255;   // segment cap, 1.5x mean

    char* p = (char*)d_ws;
    auto carve = [&](size_t bytes) {
        void* r = (void*)p;
        p += (bytes + 255) & ~(size_t)255;
        return r;
    };
    int*   rowptr = (int*)  carve((size_t)(N + 1) * 4);
    int*   col    = (int*)  carve((size_t)E * 4);
    float* dinv   = (float*)carve((size_t)N * 4);
    int*   gfill  = (int*)  carve((size_t)NB * 4);
    int*   bbase  = (int*)  carve((size_t)NB * 4);
    unsigned int* binbuf = (unsigned int*)carve((size_t)NB * C * 4);
    unsigned short* Wp_m  = (unsigned short*)carve(16384 * 2);
    unsigned short* Wp_e  = (unsigned short*)carve(16384 * 2);
    unsigned short* Wp_sd = (unsigned short*)carve(16384 * 2);
    unsigned short* Wp_md = (unsigned short*)carve(16384 * 2);
    unsigned short* A  = (unsigned short*)carve((size_t)N * 128 * 2);
    unsigned short* Bm = (unsigned short*)carve((size_t)N * 128 * 2);
    (void)ws_size;

    const int gBin = (E + BIN_CH - 1) / BIN_CH;
    const int gNode4 = (N + 3) / 4;
    const int gRow64 = (N + 63) / 64;

    // graph build
    hipMemsetAsync(gfill, 0, (size_t)NB * 4, stream);
    bin_kernel<<<gBin, 512, 0, stream>>>(src, dst, gfill, binbuf, NB, C, E);
    bscan_kernel<<<1, 64, 0, stream>>>(gfill, bbase, NB);
    build_kernel<<<NB, 256, 0, stream>>>(binbuf, gfill, bbase, rowptr, dinv, col, NB, C, N, E);

    // weight packs
    pack_kernel<<<32, 256, 0, stream>>>(W_m, W_e, W_sd, W_md, Wp_m, Wp_e, Wp_sd, Wp_md);

    // encoder
    in_gemm_kernel<<<(N * 64 + 255) / 256, 256, 0, stream>>>(x, W_s, dinv, Bm, N);
    agg_kernel<<<gNode4, 256, 0, stream>>>(Bm, rowptr, col, dinv, b_s, A, N);

    gemm_mfma_kernel<true, false><<<gRow64, 256, 0, stream>>>(A, Wp_m, nullptr, dinv, Bm, N);
    agg_kernel<<<gNode4, 256, 0, stream>>>(Bm, rowptr, col, dinv, b_m, A, N);

    gemm_mfma_kernel<true, false><<<gRow64, 256, 0, stream>>>(A, Wp_m, nullptr, dinv, Bm, N);
    agg_kernel<<<gNode4, 256, 0, stream>>>(Bm, rowptr, col, dinv, b_m, A, N);

    gemm_mfma_kernel<true, false><<<gRow64, 256, 0, stream>>>(A, Wp_e, nullptr, dinv, Bm, N);
    agg_kernel<<<gNode4, 256, 0, stream>>>(Bm, rowptr, col, dinv, b_e, A, N);

    // decoder
    gemm_mfma_kernel<false, true><<<gRow64, 256, 0, stream>>>(A, Wp_sd, b_sd, nullptr, Bm, N);
    gemm_mfma_kernel<false, true><<<gRow64, 256, 0, stream>>>(Bm, Wp_md, b_md, nullptr, A, N);
    gemm_mfma_kernel<false, true><<<gRow64, 256, 0, stream>>>(A, Wp_md, b_md, nullptr, Bm, N);
    out_kernel<<<gNode4, 256, 0, stream>>>(Bm, W_ed, b_ed, x, outp, N);
}